// Round 20
// baseline (130.535 us; speedup 1.0000x reference)
//
#include <hip/hip_runtime.h>

// ---- problem constants ----
#define NB 2          // batch
#define LT 512        // per-tensor seq len
#define LL 2048       // concatenated seq len
#define MM 4096       // NB*LL rows
#define DMODEL 512
#define DINNER 1024
#define DTRANK 32
#define DSTATE 16
#define NSEG 128
#define SEGLEN 16     // NSEG*SEGLEN == LL
#define NST (NB * DINNER * DSTATE)         // 32768 chains
#define NSCAN (NSEG * NB * DINNER)         // 262144 scan chains
#define KCH 8         // xproj K-chunks (split-K)

typedef short bf16x8 __attribute__((ext_vector_type(8)));
typedef float f32x4  __attribute__((ext_vector_type(4)));

__device__ __forceinline__ float silu_f(float x) { return x / (1.f + __expf(-x)); }
__device__ __forceinline__ unsigned short f2b(float f) {
    unsigned u = __float_as_uint(f);
    u += 0x7fffu + ((u >> 16) & 1u);   // RNE
    return (unsigned short)(u >> 16);
}
__device__ __forceinline__ float b2f(unsigned short u) {
    return __uint_as_float(((unsigned)u) << 16);
}
__device__ __forceinline__ float bhi(unsigned u) {   // high bf16 -> f32
    return __uint_as_float(u & 0xFFFF0000u);
}
__device__ __forceinline__ float blo(unsigned u) {   // low bf16 -> f32
    return __uint_as_float(u << 16);
}

// ---------------------------------------------------------------------------
// K0: fused prep: gather+cvt A-matrix, cvt in_proj_w, cvt x_proj_w.
// blocks [0,1024): xg_b; [1024,2048): wib; [2048,2112): wxb.
// ---------------------------------------------------------------------------
__global__ __launch_bounds__(256) void k_prep(
    const float* __restrict__ t0, const float* __restrict__ t1,
    const float* __restrict__ t2, const float* __restrict__ t3,
    const float* __restrict__ Wi, const float* __restrict__ Wx,
    unsigned short* __restrict__ xg_b, unsigned short* __restrict__ wib,
    unsigned short* __restrict__ wxb)
{
    const int blk = blockIdx.x;
    if (blk < 1024) {
        const int idx = blk * 256 + threadIdx.x;      // < MM*64
        const int m = idx >> 6;
        const int c8 = (idx & 63) * 8;
        const int b = m >> 11;
        const int l = m & 2047;
        const int c = l >> 7, r = l & 127;
        const int ti = c & 3, ci = c >> 2;
        const float* tp = (ti == 0) ? t0 : (ti == 1) ? t1 : (ti == 2) ? t2 : t3;
        const float* src = tp + ((size_t)b * 512 + (size_t)(ci + 4 * r)) * 512 + c8;
        float4 v0 = *(const float4*)(src + 0);
        float4 v1 = *(const float4*)(src + 4);
        bf16x8 o;
        o[0]=f2b(v0.x); o[1]=f2b(v0.y); o[2]=f2b(v0.z); o[3]=f2b(v0.w);
        o[4]=f2b(v1.x); o[5]=f2b(v1.y); o[6]=f2b(v1.z); o[7]=f2b(v1.w);
        *(bf16x8*)(xg_b + (size_t)m * DMODEL + c8) = o;
    } else if (blk < 2048) {
        const int off = (blk - 1024) * 256 + threadIdx.x;   // < 262144
        float4 v = *(const float4*)(Wi + (size_t)off * 4);
        ushort4 o;
        o.x = f2b(v.x); o.y = f2b(v.y); o.z = f2b(v.z); o.w = f2b(v.w);
        *(ushort4*)(wib + (size_t)off * 4) = o;
    } else {
        const int off = (blk - 2048) * 256 + threadIdx.x;   // < 16384
        float4 v = *(const float4*)(Wx + (size_t)off * 4);
        ushort4 o;
        o.x = f2b(v.x); o.y = f2b(v.y); o.z = f2b(v.z); o.w = f2b(v.w);
        *(ushort4*)(wxb + (size_t)off * 4) = o;
    }
}

// ---------------------------------------------------------------------------
// K1: in_proj GEMM, pure bf16 operands (xg_b, wib), 128x128 tile, 4 waves.
// n<1024 -> xc_raw (fp32, conv input); n>=1024 -> zb (bf16).
// ---------------------------------------------------------------------------
__global__ __launch_bounds__(256) void k_inproj(
    const unsigned short* __restrict__ xg_b, const unsigned short* __restrict__ wib,
    float* __restrict__ xc_raw, unsigned short* __restrict__ zb)
{
    __shared__ short As[128 * 40];   // 32 cols + 8 pad (80B row stride)
    __shared__ short Bs[128 * 40];
    const int t = threadIdx.x;
    const int lane = t & 63;
    const int wid = t >> 6;
    const int wm = wid >> 1, wn = wid & 1;
    const int bm = blockIdx.x, bn = blockIdx.y;

    const int srow  = t >> 1;          // 0..127 staging row
    const int shalf = (t & 1) * 16;    // 0 or 16 (col offset)

    const unsigned short* asrc = xg_b + (size_t)(bm * 128 + srow) * DMODEL + shalf;
    const unsigned short* bsrc = wib + (size_t)(bn * 128 + srow) * DMODEL + shalf;

    f32x4 acc[4][4];
#pragma unroll
    for (int i = 0; i < 4; ++i)
#pragma unroll
        for (int j = 0; j < 4; ++j) acc[i][j] = (f32x4){0.f, 0.f, 0.f, 0.f};

    bf16x8 ra0 = *(const bf16x8*)(asrc + 0);
    bf16x8 ra1 = *(const bf16x8*)(asrc + 8);
    bf16x8 rb0 = *(const bf16x8*)(bsrc + 0);
    bf16x8 rb1 = *(const bf16x8*)(bsrc + 8);

    const int ko = (lane >> 4) * 8;
    const int fr = lane & 15;

    for (int ks = 0; ks < DMODEL / 32; ++ks) {
        __syncthreads();
        *(bf16x8*)&As[srow * 40 + shalf]     = ra0;
        *(bf16x8*)&As[srow * 40 + shalf + 8] = ra1;
        *(bf16x8*)&Bs[srow * 40 + shalf]     = rb0;
        *(bf16x8*)&Bs[srow * 40 + shalf + 8] = rb1;
        __syncthreads();
        if (ks + 1 < DMODEL / 32) {
            const int k0 = (ks + 1) * 32;
            ra0 = *(const bf16x8*)(asrc + k0 + 0);
            ra1 = *(const bf16x8*)(asrc + k0 + 8);
            rb0 = *(const bf16x8*)(bsrc + k0 + 0);
            rb1 = *(const bf16x8*)(bsrc + k0 + 8);
        }
        bf16x8 af[4], bfr[4];
#pragma unroll
        for (int mf = 0; mf < 4; ++mf)
            af[mf] = *(const bf16x8*)&As[(wm * 64 + mf * 16 + fr) * 40 + ko];
#pragma unroll
        for (int nf = 0; nf < 4; ++nf)
            bfr[nf] = *(const bf16x8*)&Bs[(wn * 64 + nf * 16 + fr) * 40 + ko];
#pragma unroll
        for (int mf = 0; mf < 4; ++mf)
#pragma unroll
            for (int nf = 0; nf < 4; ++nf)
                acc[mf][nf] = __builtin_amdgcn_mfma_f32_16x16x32_bf16(
                    af[mf], bfr[nf], acc[mf][nf], 0, 0, 0);
    }

    if (bn < 8) {
#pragma unroll
        for (int mf = 0; mf < 4; ++mf) {
            const int gmb = bm * 128 + wm * 64 + mf * 16 + (lane >> 4) * 4;
#pragma unroll
            for (int nf = 0; nf < 4; ++nf) {
                const int gn = bn * 128 + wn * 64 + nf * 16 + (lane & 15);
#pragma unroll
                for (int j = 0; j < 4; ++j)
                    xc_raw[(size_t)(gmb + j) * DINNER + gn] = acc[mf][nf][j];
            }
        }
    } else {
#pragma unroll
        for (int mf = 0; mf < 4; ++mf) {
            const int gmb = bm * 128 + wm * 64 + mf * 16 + (lane >> 4) * 4;
#pragma unroll
            for (int nf = 0; nf < 4; ++nf) {
                const int gn = bn * 128 + wn * 64 + nf * 16 + (lane & 15) - 1024;
#pragma unroll
                for (int j = 0; j < 4; ++j)
                    zb[(size_t)(gmb + j) * DINNER + gn] = f2b(acc[mf][nf][j]);
            }
        }
    }
}

// ---------------------------------------------------------------------------
// K2: causal depthwise conv1d + bias + SiLU.
// ---------------------------------------------------------------------------
__global__ __launch_bounds__(256) void k_conv(
    const float* __restrict__ xc_raw, const float* __restrict__ cw,
    const float* __restrict__ cb, const unsigned short* __restrict__ zb,
    unsigned short* __restrict__ xc_b, unsigned int* __restrict__ xzp)
{
    const int d  = blockIdx.y * 256 + threadIdx.x;
    const int mt = blockIdx.x;               // 0..255
    const int m0 = mt * 16;
    const int l0 = m0 & 2047;                // within-batch position of row m0

    float w[4];
#pragma unroll
    for (int k = 0; k < 4; ++k) w[k] = cw[(size_t)d * 4 + k];
    const float bias = cb[d];

    float r[19];
#pragma unroll
    for (int o = 0; o < 19; ++o) {
        const int l = l0 + o - 3;
        r[o] = (l >= 0) ? xc_raw[(size_t)(m0 + o - 3) * DINNER + d] : 0.f;
    }

#pragma unroll
    for (int mm = 0; mm < 16; ++mm) {
        float s = bias;
#pragma unroll
        for (int k = 0; k < 4; ++k) s += w[k] * r[mm + k];
        const unsigned short x16 = f2b(silu_f(s));
        const size_t idx = (size_t)(m0 + mm) * DINNER + d;
        const unsigned short z16 = zb[idx];
        xc_b[idx] = x16;
        xzp[idx] = ((unsigned)z16 << 16) | (unsigned)x16;
    }
}

// ---------------------------------------------------------------------------
// K3: xproj split-K MFMA GEMM.
// ---------------------------------------------------------------------------
__global__ __launch_bounds__(256) void k_xproj_mfma(
    const unsigned short* __restrict__ xc_b, const unsigned short* __restrict__ wxb,
    float* __restrict__ part)
{
    __shared__ short As[128 * 136];   // 128 K-cols + 8 pad
    __shared__ short Bs[64 * 136];
    const int t = threadIdx.x;
    const int lane = t & 63;
    const int w = t >> 6;
    const int bm = blockIdx.x;        // 0..31
    const int kc = blockIdx.y;        // 0..7

    {
        const int row = t >> 1;
        const int cb0 = (t & 1) * 64;
        const unsigned short* src = xc_b + (size_t)(bm * 128 + row) * 1024 + kc * 128 + cb0;
#pragma unroll
        for (int q = 0; q < 8; ++q)
            *(bf16x8*)&As[row * 136 + cb0 + q * 8] = *(const bf16x8*)(src + q * 8);
    }
    {
        const int row = t >> 2;
        const int cb0 = (t & 3) * 32;
        const unsigned short* src = wxb + (size_t)row * 1024 + kc * 128 + cb0;
#pragma unroll
        for (int q = 0; q < 4; ++q)
            *(bf16x8*)&Bs[row * 136 + cb0 + q * 8] = *(const bf16x8*)(src + q * 8);
    }
    __syncthreads();

    const int fr = lane & 15;
    const int ko = (lane >> 4) * 8;

    f32x4 acc[2][4];
#pragma unroll
    for (int i = 0; i < 2; ++i)
#pragma unroll
        for (int j = 0; j < 4; ++j) acc[i][j] = (f32x4){0.f, 0.f, 0.f, 0.f};

#pragma unroll
    for (int ks = 0; ks < 4; ++ks) {
        const int kb = ks * 32 + ko;
        bf16x8 af[2], bfr[4];
#pragma unroll
        for (int mf = 0; mf < 2; ++mf)
            af[mf] = *(const bf16x8*)&As[(w * 32 + mf * 16 + fr) * 136 + kb];
#pragma unroll
        for (int nf = 0; nf < 4; ++nf)
            bfr[nf] = *(const bf16x8*)&Bs[(nf * 16 + fr) * 136 + kb];
#pragma unroll
        for (int mf = 0; mf < 2; ++mf)
#pragma unroll
            for (int nf = 0; nf < 4; ++nf)
                acc[mf][nf] = __builtin_amdgcn_mfma_f32_16x16x32_bf16(
                    af[mf], bfr[nf], acc[mf][nf], 0, 0, 0);
    }

    float* pb = part + (size_t)kc * (MM * 64);
#pragma unroll
    for (int mf = 0; mf < 2; ++mf) {
        const int rb = bm * 128 + w * 32 + mf * 16 + (lane >> 4) * 4;
#pragma unroll
        for (int nf = 0; nf < 4; ++nf) {
            const int col = nf * 16 + (lane & 15);
#pragma unroll
            for (int j = 0; j < 4; ++j)
                pb[(size_t)(rb + j) * 64 + col] = acc[mf][nf][j];
        }
    }
}

// ---------------------------------------------------------------------------
// K3b: reduce split-K partials -> dbc
// ---------------------------------------------------------------------------
__global__ __launch_bounds__(256) void k_xreduce(
    const float* __restrict__ part, float* __restrict__ dbc)
{
    const int i = blockIdx.x * 256 + threadIdx.x;    // < MM*64
    float s = 0.f;
#pragma unroll
    for (int kc = 0; kc < KCH; ++kc)
        s += part[(size_t)kc * (MM * 64) + i];
    dbc[i] = s;
}

// ---------------------------------------------------------------------------
// K4: dtproj — scalar-uniform dbc loads, fast softplus; writes flat
// dxp[m][d] = { high: bf16(delta*x), low: bf16(delta) } (coalesced dwords).
// ---------------------------------------------------------------------------
__global__ __launch_bounds__(256) void k_dtproj(
    const float* __restrict__ dbc, const float* __restrict__ dtw,
    const float* __restrict__ dtb, const unsigned short* __restrict__ xc_b,
    unsigned int* __restrict__ dxp)
{
    const int tid = threadIdx.x;
    const int m0 = blockIdx.x * 16;
    const int d  = blockIdx.y * 256 + tid;

    float w[DTRANK];
#pragma unroll
    for (int q = 0; q < 8; ++q) {
        float4 v = *(const float4*)(dtw + (size_t)d * DTRANK + q * 4);
        w[q * 4 + 0] = v.x; w[q * 4 + 1] = v.y;
        w[q * 4 + 2] = v.z; w[q * 4 + 3] = v.w;
    }
    const float bias = dtb[d];

#pragma unroll 4
    for (int m = 0; m < 16; ++m) {
        const float* bc = dbc + (size_t)(m0 + m) * 64;   // wave-uniform address
        float s0 = bias, s1 = 0.f, s2 = 0.f, s3 = 0.f;
#pragma unroll
        for (int r = 0; r < DTRANK; r += 4) {
            s0 += bc[r + 0] * w[r + 0];
            s1 += bc[r + 1] * w[r + 1];
            s2 += bc[r + 2] * w[r + 2];
            s3 += bc[r + 3] * w[r + 3];
        }
        const float s = (s0 + s1) + (s2 + s3);
        const float sp = (s > 20.f) ? s : __logf(1.f + __expf(s));
        const size_t idx = (size_t)(m0 + m) * DINNER + d;
        const float xv = b2f(xc_b[idx]);
        dxp[idx] = ((unsigned)f2b(sp * xv) << 16) | (unsigned)f2b(sp);
    }
}

// ---------------------------------------------------------------------------
// K5: scan phase A, 4-way state-split + LDS-staged segment data.
// Block covers uniform (b,g) x 64 consecutive d.  dxp staged cooperatively
// (fully coalesced) into sh_u; B rows staged into Bsh.
// ---------------------------------------------------------------------------
__global__ __launch_bounds__(256) void k_scan_partial(
    const unsigned int* __restrict__ dxp, const float* __restrict__ dbc,
    const float* __restrict__ A_log, unsigned int* __restrict__ hab)
{
    __shared__ float Bsh[16][16];        // [step][state]
    __shared__ unsigned sh_u[16][64];    // [step][dcol]
    const int tid = threadIdx.x;
    const int gid = blockIdx.x * 256 + tid;
    const int dlocal = gid & 15;
    const int sg = (gid >> 4) & 3;
    const int b = (gid >> 12) & (NB - 1);
    const int g = gid >> 13;                           // 0..127
    const int d0 = (blockIdx.x & 15) * 64;             // block's base d
    const int wv = tid >> 6;                           // wave in block = dhi_lo
    const int d = d0 + wv * 16 + dlocal;
    const int mbase = b * LL + g * SEGLEN;

    // stage B rows (256 threads, 1 elem each)
    {
        const int row = tid >> 4;
        const int cc  = tid & 15;
        Bsh[row][cc] = dbc[(size_t)(mbase + row) * 64 + 32 + cc];
    }
    // stage dxp segment block: 4 coalesced dword loads per thread
#pragma unroll
    for (int q = 0; q < 4; ++q) {
        const int idx = q * 256 + tid;
        const int row = idx >> 6, col = idx & 63;
        sh_u[row][col] = dxp[(size_t)(mbase + row) * DINNER + d0 + col];
    }

    float Af[4];
    {
        float4 a4 = *(const float4*)(A_log + d * DSTATE + sg * 4);
        Af[0] = -__expf(a4.x); Af[1] = -__expf(a4.y);
        Af[2] = -__expf(a4.z); Af[3] = -__expf(a4.w);
    }

    __syncthreads();

    unsigned uu[16];
    {
        const int col = wv * 16 + dlocal;
#pragma unroll
        for (int m = 0; m < 16; ++m) uu[m] = sh_u[m][col];
    }

    float h[4] = {0.f, 0.f, 0.f, 0.f};
    float ap[4] = {1.f, 1.f, 1.f, 1.f};

#pragma unroll
    for (int ll = 0; ll < SEGLEN; ++ll) {
        const float de = blo(uu[ll]);
        const float dx = bhi(uu[ll]);
        float4 Bv = *(const float4*)&Bsh[ll][sg * 4];
        float dA;
        dA = __expf(de * Af[0]); ap[0] *= dA; h[0] = dA * h[0] + dx * Bv.x;
        dA = __expf(de * Af[1]); ap[1] *= dA; h[1] = dA * h[1] + dx * Bv.y;
        dA = __expf(de * Af[2]); ap[2] *= dA; h[2] = dA * h[2] + dx * Bv.z;
        dA = __expf(de * Af[3]); ap[3] *= dA; h[3] = dA * h[3] + dx * Bv.w;
    }

    const size_t base = ((size_t)(b * DINNER + d) * NSEG + g) * 16 + sg * 4;
    unsigned ob[4];
#pragma unroll
    for (int q = 0; q < 4; ++q)
        ob[q] = ((unsigned)f2b(h[q]) << 16) | (unsigned)f2b(ap[q]);
    *(uint4*)&hab[base] = *(const uint4*)&ob[0];
}

// ---------------------------------------------------------------------------
// K6: combine over 128 segments, fp32 math on bf16-packed inputs.
// ---------------------------------------------------------------------------
__global__ __launch_bounds__(256) void k_scan_combine(
    const unsigned int* __restrict__ hab, unsigned short* __restrict__ hib)
{
    const int tid = blockIdx.x * 256 + threadIdx.x;   // < NB*DINNER*64
    const int g = tid & 63;
    const size_t bd = (size_t)(tid >> 6);
    const size_t base = (bd * NSEG + 2 * g) * 16;

    unsigned u0[16], u1[16];
#pragma unroll
    for (int q = 0; q < 4; ++q) {
        *(uint4*)&u0[q * 4] = *(const uint4*)&hab[base + q * 4];
        *(uint4*)&u1[q * 4] = *(const uint4*)&hab[base + 16 + q * 4];
    }

    float A0[16], B0[16], A[16], B[16];
#pragma unroll
    for (int s = 0; s < 16; ++s) {
        A0[s] = blo(u0[s]); B0[s] = bhi(u0[s]);
        const float A1 = blo(u1[s]), B1 = bhi(u1[s]);
        A[s] = A1 * A0[s];
        B[s] = A1 * B0[s] + B1;
    }
#pragma unroll
    for (int off = 1; off < 64; off <<= 1) {
#pragma unroll
        for (int s = 0; s < 16; ++s) {
            const float Ap = __shfl_up(A[s], off, 64);
            const float Bp = __shfl_up(B[s], off, 64);
            if (g >= off) { B[s] = A[s] * Bp + B[s]; A[s] = A[s] * Ap; }
        }
    }
    unsigned short E[16], E1[16];
#pragma unroll
    for (int s = 0; s < 16; ++s) {
        float e = __shfl_up(B[s], 1, 64);
        if (g == 0) e = 0.f;
        E[s]  = f2b(e);                  // h_in for segment 2g
        E1[s] = f2b(A0[s] * e + B0[s]);  // h_in for segment 2g+1
    }
#pragma unroll
    for (int q = 0; q < 2; ++q) {
        *(bf16x8*)&hib[base + q * 8]      = *(const bf16x8*)&E[q * 8];
        *(bf16x8*)&hib[base + 16 + q * 8] = *(const bf16x8*)&E1[q * 8];
    }
}

// ---------------------------------------------------------------------------
// K7: scan phase C, 4-way state-split + LDS-staged segment data.
// dxp/xzp staged cooperatively into sh_u/sh_v; B+C rows into BC.
// y reduced over sg via 2 shfl_xor; sg==0 lanes store.
// ---------------------------------------------------------------------------
__global__ __launch_bounds__(256) void k_scan_final(
    const unsigned int* __restrict__ dxp, const unsigned int* __restrict__ xzp,
    const float* __restrict__ dbc, const float* __restrict__ A_log,
    const float* __restrict__ Dp, const unsigned short* __restrict__ hib,
    unsigned short* __restrict__ yzb)
{
    __shared__ float BC[16][32];         // [step][B:0-15 | C:16-31]
    __shared__ unsigned sh_u[16][64];
    __shared__ unsigned sh_v[16][64];
    const int tid = threadIdx.x;
    const int gid = blockIdx.x * 256 + tid;
    const int dlocal = gid & 15;
    const int sg = (gid >> 4) & 3;
    const int b = (gid >> 12) & (NB - 1);
    const int g = gid >> 13;
    const int d0 = (blockIdx.x & 15) * 64;
    const int wv = tid >> 6;
    const int d = d0 + wv * 16 + dlocal;
    const int mbase = b * LL + g * SEGLEN;

    // stage BC rows: 256 threads x 2 elems
    {
#pragma unroll
        for (int q = 0; q < 2; ++q) {
            const int idx = q * 256 + tid;
            const int row = idx >> 5, cc = idx & 31;
            BC[row][cc] = dbc[(size_t)(mbase + row) * 64 + 32 + cc];
        }
    }
    // stage dxp/xzp: 4+4 coalesced dword loads per thread
#pragma unroll
    for (int q = 0; q < 4; ++q) {
        const int idx = q * 256 + tid;
        const int row = idx >> 6, col = idx & 63;
        sh_u[row][col] = dxp[(size_t)(mbase + row) * DINNER + d0 + col];
        sh_v[row][col] = xzp[(size_t)(mbase + row) * DINNER + d0 + col];
    }

    float Af[4];
    {
        float4 a4 = *(const float4*)(A_log + d * DSTATE + sg * 4);
        Af[0] = -__expf(a4.x); Af[1] = -__expf(a4.y);
        Af[2] = -__expf(a4.z); Af[3] = -__expf(a4.w);
    }
    const float Dd = Dp[d];

    float h[4];
    {
        const size_t base = ((size_t)(b * DINNER + d) * NSEG + g) * 16 + sg * 4;
        ushort4 hv = *(const ushort4*)(hib + base);
        h[0] = b2f(hv.x); h[1] = b2f(hv.y);
        h[2] = b2f(hv.z); h[3] = b2f(hv.w);
    }

    __syncthreads();

    unsigned uu[16], vv[16];
    {
        const int col = wv * 16 + dlocal;
#pragma unroll
        for (int m = 0; m < 16; ++m) {
            uu[m] = sh_u[m][col];
            vv[m] = sh_v[m][col];
        }
    }

#pragma unroll
    for (int ll = 0; ll < SEGLEN; ++ll) {
        const float de = blo(uu[ll]);
        const float dx = bhi(uu[ll]);
        const float x  = blo(vv[ll]);
        const float zz = bhi(vv[ll]);
        float4 Bv = *(const float4*)&BC[ll][sg * 4];
        float4 Cv = *(const float4*)&BC[ll][16 + sg * 4];
        float dA;
        float yp = 0.f;
        dA = __expf(de * Af[0]); h[0] = dA * h[0] + dx * Bv.x; yp += h[0] * Cv.x;
        dA = __expf(de * Af[1]); h[1] = dA * h[1] + dx * Bv.y; yp += h[1] * Cv.y;
        dA = __expf(de * Af[2]); h[2] = dA * h[2] + dx * Bv.z; yp += h[2] * Cv.z;
        dA = __expf(de * Af[3]); h[3] = dA * h[3] + dx * Bv.w; yp += h[3] * Cv.w;
        yp += __shfl_xor(yp, 16, 64);
        yp += __shfl_xor(yp, 32, 64);
        if (sg == 0)
            yzb[(size_t)(mbase + ll) * DINNER + d] = f2b((yp + Dd * x) * silu_f(zz));
    }
}

// ---------------------------------------------------------------------------
// K8: out_proj GEMM (bf16 MFMA), 64x64 tiles, grid (64,8)=512 blocks.
// ---------------------------------------------------------------------------
__global__ __launch_bounds__(256) void k_outproj(
    const unsigned short* __restrict__ yzb, const float* __restrict__ Wo,
    const float* __restrict__ t0, const float* __restrict__ t1,
    const float* __restrict__ t2, const float* __restrict__ t3,
    float* __restrict__ outp)
{
    __shared__ short As[64 * 40];   // 64 rows x (32 + 8 pad) shorts
    __shared__ short Bs[64 * 40];
    const int t = threadIdx.x;
    const int lane = t & 63;
    const int wid = t >> 6;
    const int wm = wid >> 1, wn = wid & 1;
    const int bm = blockIdx.x;      // 0..63
    const int bn = blockIdx.y;      // 0..7

    const int srow = t >> 2;          // 0..63
    const int scol = (t & 3) * 8;     // 0,8,16,24

    const unsigned short* asrc = yzb + (size_t)(bm * 64 + srow) * DINNER + scol;
    const float* bsrc = Wo + (size_t)(bn * 64 + srow) * DINNER + scol;

    f32x4 acc[2][2];
#pragma unroll
    for (int i = 0; i < 2; ++i)
#pragma unroll
        for (int j = 0; j < 2; ++j) acc[i][j] = (f32x4){0.f, 0.f, 0.f, 0.f};

    bf16x8 raA = *(const bf16x8*)asrc;
    float4 rb[2];
#pragma unroll
    for (int q = 0; q < 2; ++q) rb[q] = *(const float4*)(bsrc + q * 4);

    const int ko = (lane >> 4) * 8;
    const int fr = lane & 15;

    for (int ks = 0; ks < DINNER / 32; ++ks) {
        __syncthreads();
        {
            bf16x8 w0;
            w0[0]=f2b(rb[0].x); w0[1]=f2b(rb[0].y); w0[2]=f2b(rb[0].z); w0[3]=f2b(rb[0].w);
            w0[4]=f2b(rb[1].x); w0[5]=f2b(rb[1].y); w0[6]=f2b(rb[1].z); w0[7]=f2b(rb[1].w);
            *(bf16x8*)&As[srow * 40 + scol] = raA;
            *(bf16x8*)&Bs[srow * 40 + scol] = w0;
        }
        __syncthreads();
        if (ks + 1 < DINNER / 32) {
            const int k0 = (ks + 1) * 32;
            raA = *(const bf16x8*)(asrc + k0);
#pragma unroll
            for (int q = 0; q < 2; ++q) rb[q] = *(const float4*)(bsrc + k0 + q * 4);
        }
        bf16x8 af[2], bfr[2];
#pragma unroll
        for (int mf = 0; mf < 2; ++mf)
            af[mf] = *(const bf16x8*)&As[(wm * 32 + mf * 16 + fr) * 40 + ko];
#pragma unroll
        for (int nf = 0; nf < 2; ++nf)
            bfr[nf] = *(const bf16x8*)&Bs[(wn * 32 + nf * 16 + fr) * 40 + ko];
#pragma unroll
        for (int mf = 0; mf < 2; ++mf)
#pragma unroll
            for (int nf = 0; nf < 2; ++nf)
                acc[mf][nf] = __builtin_amdgcn_mfma_f32_16x16x32_bf16(
                    af[mf], bfr[nf], acc[mf][nf], 0, 0, 0);
    }

#pragma unroll
    for (int mf = 0; mf < 2; ++mf) {
#pragma unroll
        for (int j = 0; j < 4; ++j) {
            const int gm = bm * 64 + wm * 32 + mf * 16 + (lane >> 4) * 4 + j;
            const int b = gm >> 11;
            const int l = gm & 2047;
            const int ii = l & 3;
            const int jj = l >> 2;
            const float* tsel = (ii == 0) ? t0 : (ii == 1) ? t1 : (ii == 2) ? t2 : t3;
#pragma unroll
            for (int nf = 0; nf < 2; ++nf) {
                const int gn = bn * 64 + wn * 32 + nf * 16 + (lane & 15);
                const float tv = tsel[((size_t)b * 512 + jj) * 512 + gn];
                outp[(((size_t)ii * NB + b) * 512 + jj) * 512 + gn] = acc[mf][nf][j] + tv;
            }
        }
    }
}

// ---------------------------------------------------------------------------
extern "C" void kernel_launch(void* const* d_in, const int* in_sizes, int n_in,
                              void* d_out, int out_size, void* d_ws, size_t ws_size,
                              hipStream_t stream)
{
    const float* t0 = (const float*)d_in[0];
    const float* t1 = (const float*)d_in[1];
    const float* t2 = (const float*)d_in[2];
    const float* t3 = (const float*)d_in[3];
    const float* in_proj_w  = (const float*)d_in[4];
    const float* conv_w     = (const float*)d_in[5];
    const float* conv_b     = (const float*)d_in[6];
    const float* x_proj_w   = (const float*)d_in[7];
    const float* dt_w       = (const float*)d_in[8];
    const float* dt_b       = (const float*)d_in[9];
    const float* A_log      = (const float*)d_in[10];
    const float* D_param    = (const float*)d_in[11];
    const float* out_proj_w = (const float*)d_in[12];
    float* outp = (float*)d_out;

    // workspace carve (~69 MB).  Aliasing timeline (stream-ordered, audited):
    // 1 prep:     W xg_b (@dxp), wib (@xzp), wxb (@hib region)
    // 2 inproj:   R xg_b, wib    -> W xc_raw(f32), zb (@hab region)
    // 3 conv:     R xc_raw, zb   -> W xc_b, xzp (clobbers wib - dead)
    // 4 xproj:    R xc_b, wxb    -> W part (@xc_raw; xc_raw dead)
    // 5 xreduce:  R part         -> W dbc
    // 6 dtproj:   R dbc, xc_b    -> W dxp (clobbers xg_b - dead)
    // 7 scanA:    R dxp, dbc     -> W hab (clobbers zb - dead)
    // 8 combine:  R hab          -> W hib (clobbers wxb - dead)
    // 9 scanC:    R dxp, xzp, dbc, hib -> W yzb (@xc_raw; part dead)
    // 10 outproj: R yzb, Wo, t*  -> W outp
    float* xc_raw = (float*)d_ws;                                    // 16MB
    unsigned short* xc_b = (unsigned short*)(xc_raw + (size_t)MM * DINNER);  // 8MB
    unsigned int* dxp = (unsigned int*)(xc_b + (size_t)MM * DINNER);         // 16MB
    unsigned int* xzp = dxp + (size_t)MM * DINNER;                   // 16MB
    float* dbc  = (float*)(xzp + (size_t)MM * DINNER);               // 1MB
    unsigned int* hab = (unsigned int*)(dbc + (size_t)MM * 64);      // 8MB
    unsigned short* hib = (unsigned short*)(hab + (size_t)NB * DINNER * NSEG * 16); // 4MB
    float* part  = xc_raw;                                           // alias (8MB)
    unsigned short* yzb = (unsigned short*)xc_raw;                   // alias (8MB)
    unsigned short* zb  = (unsigned short*)hab;                      // alias (8MB)
    unsigned short* wxb = hib;                                       // alias (128KB)
    unsigned short* xg_b = (unsigned short*)dxp;                     // alias (4MB)
    unsigned short* wib  = (unsigned short*)xzp;                     // alias (2MB)

    k_prep<<<2112, 256, 0, stream>>>(t0, t1, t2, t3, in_proj_w, x_proj_w, xg_b, wib, wxb);
    k_inproj<<<dim3(32, 16), 256, 0, stream>>>(xg_b, wib, xc_raw, zb);
    k_conv<<<dim3(MM / 16, 4), 256, 0, stream>>>(xc_raw, conv_w, conv_b, zb, xc_b, xzp);
    k_xproj_mfma<<<dim3(32, KCH), 256, 0, stream>>>(xc_b, wxb, part);
    k_xreduce<<<(MM * 64) / 256, 256, 0, stream>>>(part, dbc);
    k_dtproj<<<dim3(MM / 16, 4), 256, 0, stream>>>(dbc, dt_w, dt_b, xc_b, dxp);
    k_scan_partial<<<(NSCAN * 4) / 256, 256, 0, stream>>>(dxp, dbc, A_log, hab);
    k_scan_combine<<<(NB * DINNER * 64) / 256, 256, 0, stream>>>(hab, hib);
    k_scan_final<<<(NSCAN * 4) / 256, 256, 0, stream>>>(dxp, xzp, dbc, A_log, D_param, hib, yzb);
    k_outproj<<<dim3(64, 8), 256, 0, stream>>>(yzb, out_proj_w, t0, t1, t2, t3, outp);
}

// Round 21
// 127.493 us; speedup vs baseline: 1.0239x; 1.0239x over previous
//
#include <hip/hip_runtime.h>

// ---- problem constants ----
#define NB 2          // batch
#define LT 512        // per-tensor seq len
#define LL 2048       // concatenated seq len
#define MM 4096       // NB*LL rows
#define DMODEL 512
#define DINNER 1024
#define DTRANK 32
#define DSTATE 16
#define NSEG 128
#define SEGLEN 16     // NSEG*SEGLEN == LL
#define NST (NB * DINNER * DSTATE)         // 32768 chains
#define NSCAN (NSEG * NB * DINNER)         // 262144 scan chains
#define KCH 8         // xproj K-chunks (split-K)

typedef short bf16x8 __attribute__((ext_vector_type(8)));
typedef float f32x4  __attribute__((ext_vector_type(4)));

__device__ __forceinline__ float silu_f(float x) { return x / (1.f + __expf(-x)); }
__device__ __forceinline__ unsigned short f2b(float f) {
    unsigned u = __float_as_uint(f);
    u += 0x7fffu + ((u >> 16) & 1u);   // RNE
    return (unsigned short)(u >> 16);
}
__device__ __forceinline__ float b2f(unsigned short u) {
    return __uint_as_float(((unsigned)u) << 16);
}
__device__ __forceinline__ float bhi(unsigned u) {   // high bf16 -> f32
    return __uint_as_float(u & 0xFFFF0000u);
}
__device__ __forceinline__ float blo(unsigned u) {   // low bf16 -> f32
    return __uint_as_float(u << 16);
}

// ---------------------------------------------------------------------------
// K0: fused prep: gather+cvt A-matrix, cvt in_proj_w, cvt x_proj_w.
// blocks [0,1024): xg_b; [1024,2048): wib; [2048,2112): wxb.
// ---------------------------------------------------------------------------
__global__ __launch_bounds__(256) void k_prep(
    const float* __restrict__ t0, const float* __restrict__ t1,
    const float* __restrict__ t2, const float* __restrict__ t3,
    const float* __restrict__ Wi, const float* __restrict__ Wx,
    unsigned short* __restrict__ xg_b, unsigned short* __restrict__ wib,
    unsigned short* __restrict__ wxb)
{
    const int blk = blockIdx.x;
    if (blk < 1024) {
        const int idx = blk * 256 + threadIdx.x;      // < MM*64
        const int m = idx >> 6;
        const int c8 = (idx & 63) * 8;
        const int b = m >> 11;
        const int l = m & 2047;
        const int c = l >> 7, r = l & 127;
        const int ti = c & 3, ci = c >> 2;
        const float* tp = (ti == 0) ? t0 : (ti == 1) ? t1 : (ti == 2) ? t2 : t3;
        const float* src = tp + ((size_t)b * 512 + (size_t)(ci + 4 * r)) * 512 + c8;
        float4 v0 = *(const float4*)(src + 0);
        float4 v1 = *(const float4*)(src + 4);
        bf16x8 o;
        o[0]=f2b(v0.x); o[1]=f2b(v0.y); o[2]=f2b(v0.z); o[3]=f2b(v0.w);
        o[4]=f2b(v1.x); o[5]=f2b(v1.y); o[6]=f2b(v1.z); o[7]=f2b(v1.w);
        *(bf16x8*)(xg_b + (size_t)m * DMODEL + c8) = o;
    } else if (blk < 2048) {
        const int off = (blk - 1024) * 256 + threadIdx.x;   // < 262144
        float4 v = *(const float4*)(Wi + (size_t)off * 4);
        ushort4 o;
        o.x = f2b(v.x); o.y = f2b(v.y); o.z = f2b(v.z); o.w = f2b(v.w);
        *(ushort4*)(wib + (size_t)off * 4) = o;
    } else {
        const int off = (blk - 2048) * 256 + threadIdx.x;   // < 16384
        float4 v = *(const float4*)(Wx + (size_t)off * 4);
        ushort4 o;
        o.x = f2b(v.x); o.y = f2b(v.y); o.z = f2b(v.z); o.w = f2b(v.w);
        *(ushort4*)(wxb + (size_t)off * 4) = o;
    }
}

// ---------------------------------------------------------------------------
// K1: in_proj GEMM, pure bf16 operands (xg_b, wib), 128x128 tile, 4 waves.
// n<1024 -> xc_raw (fp32, conv input); n>=1024 -> zb (bf16).
// ---------------------------------------------------------------------------
__global__ __launch_bounds__(256) void k_inproj(
    const unsigned short* __restrict__ xg_b, const unsigned short* __restrict__ wib,
    float* __restrict__ xc_raw, unsigned short* __restrict__ zb)
{
    __shared__ short As[128 * 40];   // 32 cols + 8 pad (80B row stride)
    __shared__ short Bs[128 * 40];
    const int t = threadIdx.x;
    const int lane = t & 63;
    const int wid = t >> 6;
    const int wm = wid >> 1, wn = wid & 1;
    const int bm = blockIdx.x, bn = blockIdx.y;

    const int srow  = t >> 1;          // 0..127 staging row
    const int shalf = (t & 1) * 16;    // 0 or 16 (col offset)

    const unsigned short* asrc = xg_b + (size_t)(bm * 128 + srow) * DMODEL + shalf;
    const unsigned short* bsrc = wib + (size_t)(bn * 128 + srow) * DMODEL + shalf;

    f32x4 acc[4][4];
#pragma unroll
    for (int i = 0; i < 4; ++i)
#pragma unroll
        for (int j = 0; j < 4; ++j) acc[i][j] = (f32x4){0.f, 0.f, 0.f, 0.f};

    bf16x8 ra0 = *(const bf16x8*)(asrc + 0);
    bf16x8 ra1 = *(const bf16x8*)(asrc + 8);
    bf16x8 rb0 = *(const bf16x8*)(bsrc + 0);
    bf16x8 rb1 = *(const bf16x8*)(bsrc + 8);

    const int ko = (lane >> 4) * 8;
    const int fr = lane & 15;

    for (int ks = 0; ks < DMODEL / 32; ++ks) {
        __syncthreads();
        *(bf16x8*)&As[srow * 40 + shalf]     = ra0;
        *(bf16x8*)&As[srow * 40 + shalf + 8] = ra1;
        *(bf16x8*)&Bs[srow * 40 + shalf]     = rb0;
        *(bf16x8*)&Bs[srow * 40 + shalf + 8] = rb1;
        __syncthreads();
        if (ks + 1 < DMODEL / 32) {
            const int k0 = (ks + 1) * 32;
            ra0 = *(const bf16x8*)(asrc + k0 + 0);
            ra1 = *(const bf16x8*)(asrc + k0 + 8);
            rb0 = *(const bf16x8*)(bsrc + k0 + 0);
            rb1 = *(const bf16x8*)(bsrc + k0 + 8);
        }
        bf16x8 af[4], bfr[4];
#pragma unroll
        for (int mf = 0; mf < 4; ++mf)
            af[mf] = *(const bf16x8*)&As[(wm * 64 + mf * 16 + fr) * 40 + ko];
#pragma unroll
        for (int nf = 0; nf < 4; ++nf)
            bfr[nf] = *(const bf16x8*)&Bs[(wn * 64 + nf * 16 + fr) * 40 + ko];
#pragma unroll
        for (int mf = 0; mf < 4; ++mf)
#pragma unroll
            for (int nf = 0; nf < 4; ++nf)
                acc[mf][nf] = __builtin_amdgcn_mfma_f32_16x16x32_bf16(
                    af[mf], bfr[nf], acc[mf][nf], 0, 0, 0);
    }

    if (bn < 8) {
#pragma unroll
        for (int mf = 0; mf < 4; ++mf) {
            const int gmb = bm * 128 + wm * 64 + mf * 16 + (lane >> 4) * 4;
#pragma unroll
            for (int nf = 0; nf < 4; ++nf) {
                const int gn = bn * 128 + wn * 64 + nf * 16 + (lane & 15);
#pragma unroll
                for (int j = 0; j < 4; ++j)
                    xc_raw[(size_t)(gmb + j) * DINNER + gn] = acc[mf][nf][j];
            }
        }
    } else {
#pragma unroll
        for (int mf = 0; mf < 4; ++mf) {
            const int gmb = bm * 128 + wm * 64 + mf * 16 + (lane >> 4) * 4;
#pragma unroll
            for (int nf = 0; nf < 4; ++nf) {
                const int gn = bn * 128 + wn * 64 + nf * 16 + (lane & 15) - 1024;
#pragma unroll
                for (int j = 0; j < 4; ++j)
                    zb[(size_t)(gmb + j) * DINNER + gn] = f2b(acc[mf][nf][j]);
            }
        }
    }
}

// ---------------------------------------------------------------------------
// K2: causal depthwise conv1d + bias + SiLU.
// ---------------------------------------------------------------------------
__global__ __launch_bounds__(256) void k_conv(
    const float* __restrict__ xc_raw, const float* __restrict__ cw,
    const float* __restrict__ cb, const unsigned short* __restrict__ zb,
    unsigned short* __restrict__ xc_b, unsigned int* __restrict__ xzp)
{
    const int d  = blockIdx.y * 256 + threadIdx.x;
    const int mt = blockIdx.x;               // 0..255
    const int m0 = mt * 16;
    const int l0 = m0 & 2047;                // within-batch position of row m0

    float w[4];
#pragma unroll
    for (int k = 0; k < 4; ++k) w[k] = cw[(size_t)d * 4 + k];
    const float bias = cb[d];

    float r[19];
#pragma unroll
    for (int o = 0; o < 19; ++o) {
        const int l = l0 + o - 3;
        r[o] = (l >= 0) ? xc_raw[(size_t)(m0 + o - 3) * DINNER + d] : 0.f;
    }

#pragma unroll
    for (int mm = 0; mm < 16; ++mm) {
        float s = bias;
#pragma unroll
        for (int k = 0; k < 4; ++k) s += w[k] * r[mm + k];
        const unsigned short x16 = f2b(silu_f(s));
        const size_t idx = (size_t)(m0 + mm) * DINNER + d;
        const unsigned short z16 = zb[idx];
        xc_b[idx] = x16;
        xzp[idx] = ((unsigned)z16 << 16) | (unsigned)x16;
    }
}

// ---------------------------------------------------------------------------
// K3: xproj split-K MFMA GEMM.
// ---------------------------------------------------------------------------
__global__ __launch_bounds__(256) void k_xproj_mfma(
    const unsigned short* __restrict__ xc_b, const unsigned short* __restrict__ wxb,
    float* __restrict__ part)
{
    __shared__ short As[128 * 136];   // 128 K-cols + 8 pad
    __shared__ short Bs[64 * 136];
    const int t = threadIdx.x;
    const int lane = t & 63;
    const int w = t >> 6;
    const int bm = blockIdx.x;        // 0..31
    const int kc = blockIdx.y;        // 0..7

    {
        const int row = t >> 1;
        const int cb0 = (t & 1) * 64;
        const unsigned short* src = xc_b + (size_t)(bm * 128 + row) * 1024 + kc * 128 + cb0;
#pragma unroll
        for (int q = 0; q < 8; ++q)
            *(bf16x8*)&As[row * 136 + cb0 + q * 8] = *(const bf16x8*)(src + q * 8);
    }
    {
        const int row = t >> 2;
        const int cb0 = (t & 3) * 32;
        const unsigned short* src = wxb + (size_t)row * 1024 + kc * 128 + cb0;
#pragma unroll
        for (int q = 0; q < 4; ++q)
            *(bf16x8*)&Bs[row * 136 + cb0 + q * 8] = *(const bf16x8*)(src + q * 8);
    }
    __syncthreads();

    const int fr = lane & 15;
    const int ko = (lane >> 4) * 8;

    f32x4 acc[2][4];
#pragma unroll
    for (int i = 0; i < 2; ++i)
#pragma unroll
        for (int j = 0; j < 4; ++j) acc[i][j] = (f32x4){0.f, 0.f, 0.f, 0.f};

#pragma unroll
    for (int ks = 0; ks < 4; ++ks) {
        const int kb = ks * 32 + ko;
        bf16x8 af[2], bfr[4];
#pragma unroll
        for (int mf = 0; mf < 2; ++mf)
            af[mf] = *(const bf16x8*)&As[(w * 32 + mf * 16 + fr) * 136 + kb];
#pragma unroll
        for (int nf = 0; nf < 4; ++nf)
            bfr[nf] = *(const bf16x8*)&Bs[(nf * 16 + fr) * 136 + kb];
#pragma unroll
        for (int mf = 0; mf < 2; ++mf)
#pragma unroll
            for (int nf = 0; nf < 4; ++nf)
                acc[mf][nf] = __builtin_amdgcn_mfma_f32_16x16x32_bf16(
                    af[mf], bfr[nf], acc[mf][nf], 0, 0, 0);
    }

    float* pb = part + (size_t)kc * (MM * 64);
#pragma unroll
    for (int mf = 0; mf < 2; ++mf) {
        const int rb = bm * 128 + w * 32 + mf * 16 + (lane >> 4) * 4;
#pragma unroll
        for (int nf = 0; nf < 4; ++nf) {
            const int col = nf * 16 + (lane & 15);
#pragma unroll
            for (int j = 0; j < 4; ++j)
                pb[(size_t)(rb + j) * 64 + col] = acc[mf][nf][j];
        }
    }
}

// ---------------------------------------------------------------------------
// K3b: reduce split-K partials -> dbc
// ---------------------------------------------------------------------------
__global__ __launch_bounds__(256) void k_xreduce(
    const float* __restrict__ part, float* __restrict__ dbc)
{
    const int i = blockIdx.x * 256 + threadIdx.x;    // < MM*64
    float s = 0.f;
#pragma unroll
    for (int kc = 0; kc < KCH; ++kc)
        s += part[(size_t)kc * (MM * 64) + i];
    dbc[i] = s;
}

// ---------------------------------------------------------------------------
// K4: dtproj — scalar-uniform dbc loads, fast softplus; writes flat
// dxp[m][d] = { high: bf16(delta*x), low: bf16(delta) } (coalesced dwords).
// ---------------------------------------------------------------------------
__global__ __launch_bounds__(256) void k_dtproj(
    const float* __restrict__ dbc, const float* __restrict__ dtw,
    const float* __restrict__ dtb, const unsigned short* __restrict__ xc_b,
    unsigned int* __restrict__ dxp)
{
    const int tid = threadIdx.x;
    const int m0 = blockIdx.x * 16;
    const int d  = blockIdx.y * 256 + tid;

    float w[DTRANK];
#pragma unroll
    for (int q = 0; q < 8; ++q) {
        float4 v = *(const float4*)(dtw + (size_t)d * DTRANK + q * 4);
        w[q * 4 + 0] = v.x; w[q * 4 + 1] = v.y;
        w[q * 4 + 2] = v.z; w[q * 4 + 3] = v.w;
    }
    const float bias = dtb[d];

#pragma unroll 4
    for (int m = 0; m < 16; ++m) {
        const float* bc = dbc + (size_t)(m0 + m) * 64;   // wave-uniform address
        float s0 = bias, s1 = 0.f, s2 = 0.f, s3 = 0.f;
#pragma unroll
        for (int r = 0; r < DTRANK; r += 4) {
            s0 += bc[r + 0] * w[r + 0];
            s1 += bc[r + 1] * w[r + 1];
            s2 += bc[r + 2] * w[r + 2];
            s3 += bc[r + 3] * w[r + 3];
        }
        const float s = (s0 + s1) + (s2 + s3);
        const float sp = (s > 20.f) ? s : __logf(1.f + __expf(s));
        const size_t idx = (size_t)(m0 + m) * DINNER + d;
        const float xv = b2f(xc_b[idx]);
        dxp[idx] = ((unsigned)f2b(sp * xv) << 16) | (unsigned)f2b(sp);
    }
}

// ---------------------------------------------------------------------------
// K5: scan phase A. 16-step segment preloaded upfront (coalesced dwords);
// B-rows staged to LDS once per wave (broadcast ds_reads per step — no
// per-step global/scalar loads). Writes packed bf16 hab[bd][g][s].
// ---------------------------------------------------------------------------
__global__ __launch_bounds__(256) void k_scan_partial(
    const unsigned int* __restrict__ dxp, const float* __restrict__ dbc,
    const float* __restrict__ A_log, unsigned int* __restrict__ hab)
{
    __shared__ float Bsh[4][16][16];   // [wave][step][state]
    const int gid = blockIdx.x * 256 + threadIdx.x;   // < NSCAN
    const int d = gid & 1023;
    const int b = (gid >> 10) & (NB - 1);
    const int g = gid >> 11;                           // 0..127
    const int w = threadIdx.x >> 6;
    const int lane = threadIdx.x & 63;

    const int mbase = b * LL + g * SEGLEN;

    // stage the wave's 16 B-rows (uniform (b,g) per wave): 4 rows/instr.
    {
        const int r0 = lane >> 4;        // 0..3
        const int cc = lane & 15;
#pragma unroll
        for (int rq = 0; rq < 4; ++rq) {
            const int row = rq * 4 + r0;
            Bsh[w][row][cc] = dbc[(size_t)(mbase + row) * 64 + 32 + cc];
        }
    }

    float Af[DSTATE];
#pragma unroll
    for (int q = 0; q < 4; ++q) {
        float4 a4 = *(const float4*)(A_log + d * DSTATE + q * 4);
        Af[q * 4 + 0] = -__expf(a4.x);
        Af[q * 4 + 1] = -__expf(a4.y);
        Af[q * 4 + 2] = -__expf(a4.z);
        Af[q * 4 + 3] = -__expf(a4.w);
    }

    unsigned uu[16];
#pragma unroll
    for (int m = 0; m < 16; ++m)
        uu[m] = dxp[(size_t)(mbase + m) * DINNER + d];

    __syncthreads();

    float h[DSTATE], ap[DSTATE];
#pragma unroll
    for (int s = 0; s < DSTATE; ++s) { h[s] = 0.f; ap[s] = 1.f; }

#pragma unroll
    for (int ll = 0; ll < SEGLEN; ++ll) {
        const float de = blo(uu[ll]);
        const float dx = bhi(uu[ll]);
        float Bv[DSTATE];
#pragma unroll
        for (int q = 0; q < 4; ++q)
            *(float4*)&Bv[q * 4] = *(const float4*)&Bsh[w][ll][q * 4];
#pragma unroll
        for (int s = 0; s < DSTATE; ++s) {
            const float dA = __expf(de * Af[s]);
            ap[s] *= dA;
            h[s] = dA * h[s] + dx * Bv[s];
        }
    }

    const size_t base = ((size_t)(b * DINNER + d) * NSEG + g) * 16;
    unsigned ob[16];
#pragma unroll
    for (int s = 0; s < DSTATE; ++s)
        ob[s] = ((unsigned)f2b(h[s]) << 16) | (unsigned)f2b(ap[s]);
#pragma unroll
    for (int q = 0; q < 4; ++q)
        *(uint4*)&hab[base + q * 4] = *(const uint4*)&ob[q * 4];
}

// ---------------------------------------------------------------------------
// K6: combine over 128 segments, fp32 math on bf16-packed inputs.
// One wave per bd; lane g owns segments {2g, 2g+1} x all 16 s.
// Writes h_in (bf16) to hib[bd][g][s].
// ---------------------------------------------------------------------------
__global__ __launch_bounds__(256) void k_scan_combine(
    const unsigned int* __restrict__ hab, unsigned short* __restrict__ hib)
{
    const int tid = blockIdx.x * 256 + threadIdx.x;   // < NB*DINNER*64
    const int g = tid & 63;
    const size_t bd = (size_t)(tid >> 6);
    const size_t base = (bd * NSEG + 2 * g) * 16;

    unsigned u0[16], u1[16];
#pragma unroll
    for (int q = 0; q < 4; ++q) {
        *(uint4*)&u0[q * 4] = *(const uint4*)&hab[base + q * 4];
        *(uint4*)&u1[q * 4] = *(const uint4*)&hab[base + 16 + q * 4];
    }

    float A0[16], B0[16], A[16], B[16];
#pragma unroll
    for (int s = 0; s < 16; ++s) {
        A0[s] = blo(u0[s]); B0[s] = bhi(u0[s]);
        const float A1 = blo(u1[s]), B1 = bhi(u1[s]);
        A[s] = A1 * A0[s];
        B[s] = A1 * B0[s] + B1;
    }
#pragma unroll
    for (int off = 1; off < 64; off <<= 1) {
#pragma unroll
        for (int s = 0; s < 16; ++s) {
            const float Ap = __shfl_up(A[s], off, 64);
            const float Bp = __shfl_up(B[s], off, 64);
            if (g >= off) { B[s] = A[s] * Bp + B[s]; A[s] = A[s] * Ap; }
        }
    }
    unsigned short E[16], E1[16];
#pragma unroll
    for (int s = 0; s < 16; ++s) {
        float e = __shfl_up(B[s], 1, 64);
        if (g == 0) e = 0.f;
        E[s]  = f2b(e);                  // h_in for segment 2g
        E1[s] = f2b(A0[s] * e + B0[s]);  // h_in for segment 2g+1
    }
#pragma unroll
    for (int q = 0; q < 2; ++q) {
        *(bf16x8*)&hib[base + q * 8]      = *(const bf16x8*)&E[q * 8];
        *(bf16x8*)&hib[base + 16 + q * 8] = *(const bf16x8*)&E1[q * 8];
    }
}

// ---------------------------------------------------------------------------
// K7: scan phase C. Segment preload (16+16 coalesced dwords) + bf16 h_in;
// B+C rows staged to LDS once per wave (broadcast reads per step);
// coalesced yzb stores.
// ---------------------------------------------------------------------------
__global__ __launch_bounds__(256) void k_scan_final(
    const unsigned int* __restrict__ dxp, const unsigned int* __restrict__ xzp,
    const float* __restrict__ dbc, const float* __restrict__ A_log,
    const float* __restrict__ Dp, const unsigned short* __restrict__ hib,
    unsigned short* __restrict__ yzb)
{
    __shared__ float BC[4][16][32];   // [wave][step][B:0-15 | C:16-31]
    const int gid = blockIdx.x * 256 + threadIdx.x;   // < NSCAN
    const int d = gid & 1023;
    const int b = (gid >> 10) & (NB - 1);
    const int g = gid >> 11;
    const int w = threadIdx.x >> 6;
    const int lane = threadIdx.x & 63;

    const int mbase = b * LL + g * SEGLEN;

    // stage the wave's 16 (B|C) rows: dbc cols 32..63 contiguous, 2 rows/instr.
    {
        const int r0 = lane >> 5;        // 0..1
        const int cc = lane & 31;
#pragma unroll
        for (int rq = 0; rq < 8; ++rq) {
            const int row = rq * 2 + r0;
            BC[w][row][cc] = dbc[(size_t)(mbase + row) * 64 + 32 + cc];
        }
    }

    float Af[DSTATE];
#pragma unroll
    for (int q = 0; q < 4; ++q) {
        float4 a4 = *(const float4*)(A_log + d * DSTATE + q * 4);
        Af[q * 4 + 0] = -__expf(a4.x);
        Af[q * 4 + 1] = -__expf(a4.y);
        Af[q * 4 + 2] = -__expf(a4.z);
        Af[q * 4 + 3] = -__expf(a4.w);
    }
    const float Dd = Dp[d];

    unsigned uu[16], vv[16];
#pragma unroll
    for (int m = 0; m < 16; ++m) {
        uu[m] = dxp[(size_t)(mbase + m) * DINNER + d];
        vv[m] = xzp[(size_t)(mbase + m) * DINNER + d];
    }

    float h[DSTATE];
    {
        const size_t base = ((size_t)(b * DINNER + d) * NSEG + g) * 16;
        bf16x8 h0 = *(const bf16x8*)&hib[base];
        bf16x8 h1 = *(const bf16x8*)&hib[base + 8];
#pragma unroll
        for (int s = 0; s < 8; ++s) {
            h[s]     = b2f((unsigned short)h0[s]);
            h[s + 8] = b2f((unsigned short)h1[s]);
        }
    }

    __syncthreads();

#pragma unroll
    for (int ll = 0; ll < SEGLEN; ++ll) {
        const float de = blo(uu[ll]);
        const float dx = bhi(uu[ll]);
        const float x  = blo(vv[ll]);
        const float zz = bhi(vv[ll]);
        float Bv[DSTATE], Cv[DSTATE];
#pragma unroll
        for (int q = 0; q < 4; ++q) {
            *(float4*)&Bv[q * 4] = *(const float4*)&BC[w][ll][q * 4];
            *(float4*)&Cv[q * 4] = *(const float4*)&BC[w][ll][16 + q * 4];
        }
        float y0 = 0.f, y1 = 0.f, y2 = 0.f, y3 = 0.f;
#pragma unroll
        for (int s = 0; s < DSTATE; s += 4) {
            float dA;
            dA = __expf(de * Af[s + 0]); h[s + 0] = dA * h[s + 0] + dx * Bv[s + 0]; y0 += h[s + 0] * Cv[s + 0];
            dA = __expf(de * Af[s + 1]); h[s + 1] = dA * h[s + 1] + dx * Bv[s + 1]; y1 += h[s + 1] * Cv[s + 1];
            dA = __expf(de * Af[s + 2]); h[s + 2] = dA * h[s + 2] + dx * Bv[s + 2]; y2 += h[s + 2] * Cv[s + 2];
            dA = __expf(de * Af[s + 3]); h[s + 3] = dA * h[s + 3] + dx * Bv[s + 3]; y3 += h[s + 3] * Cv[s + 3];
        }
        const float y = (y0 + y1) + (y2 + y3);
        yzb[(size_t)(mbase + ll) * DINNER + d] = f2b((y + Dd * x) * silu_f(zz));
    }
}

// ---------------------------------------------------------------------------
// K8: out_proj GEMM (bf16 MFMA), 64x64 tiles, grid (64,8)=512 blocks.
// ---------------------------------------------------------------------------
__global__ __launch_bounds__(256) void k_outproj(
    const unsigned short* __restrict__ yzb, const float* __restrict__ Wo,
    const float* __restrict__ t0, const float* __restrict__ t1,
    const float* __restrict__ t2, const float* __restrict__ t3,
    float* __restrict__ outp)
{
    __shared__ short As[64 * 40];   // 64 rows x (32 + 8 pad) shorts
    __shared__ short Bs[64 * 40];
    const int t = threadIdx.x;
    const int lane = t & 63;
    const int wid = t >> 6;
    const int wm = wid >> 1, wn = wid & 1;
    const int bm = blockIdx.x;      // 0..63
    const int bn = blockIdx.y;      // 0..7

    const int srow = t >> 2;          // 0..63
    const int scol = (t & 3) * 8;     // 0,8,16,24

    const unsigned short* asrc = yzb + (size_t)(bm * 64 + srow) * DINNER + scol;
    const float* bsrc = Wo + (size_t)(bn * 64 + srow) * DINNER + scol;

    f32x4 acc[2][2];
#pragma unroll
    for (int i = 0; i < 2; ++i)
#pragma unroll
        for (int j = 0; j < 2; ++j) acc[i][j] = (f32x4){0.f, 0.f, 0.f, 0.f};

    bf16x8 raA = *(const bf16x8*)asrc;
    float4 rb[2];
#pragma unroll
    for (int q = 0; q < 2; ++q) rb[q] = *(const float4*)(bsrc + q * 4);

    const int ko = (lane >> 4) * 8;
    const int fr = lane & 15;

    for (int ks = 0; ks < DINNER / 32; ++ks) {
        __syncthreads();
        {
            bf16x8 w0;
            w0[0]=f2b(rb[0].x); w0[1]=f2b(rb[0].y); w0[2]=f2b(rb[0].z); w0[3]=f2b(rb[0].w);
            w0[4]=f2b(rb[1].x); w0[5]=f2b(rb[1].y); w0[6]=f2b(rb[1].z); w0[7]=f2b(rb[1].w);
            *(bf16x8*)&As[srow * 40 + scol] = raA;
            *(bf16x8*)&Bs[srow * 40 + scol] = w0;
        }
        __syncthreads();
        if (ks + 1 < DINNER / 32) {
            const int k0 = (ks + 1) * 32;
            raA = *(const bf16x8*)(asrc + k0);
#pragma unroll
            for (int q = 0; q < 2; ++q) rb[q] = *(const float4*)(bsrc + k0 + q * 4);
        }
        bf16x8 af[2], bfr[2];
#pragma unroll
        for (int mf = 0; mf < 2; ++mf)
            af[mf] = *(const bf16x8*)&As[(wm * 32 + mf * 16 + fr) * 40 + ko];
#pragma unroll
        for (int nf = 0; nf < 2; ++nf)
            bfr[nf] = *(const bf16x8*)&Bs[(wn * 32 + nf * 16 + fr) * 40 + ko];
#pragma unroll
        for (int mf = 0; mf < 2; ++mf)
#pragma unroll
            for (int nf = 0; nf < 2; ++nf)
                acc[mf][nf] = __builtin_amdgcn_mfma_f32_16x16x32_bf16(
                    af[mf], bfr[nf], acc[mf][nf], 0, 0, 0);
    }

#pragma unroll
    for (int mf = 0; mf < 2; ++mf) {
#pragma unroll
        for (int j = 0; j < 4; ++j) {
            const int gm = bm * 64 + wm * 32 + mf * 16 + (lane >> 4) * 4 + j;
            const int b = gm >> 11;
            const int l = gm & 2047;
            const int ii = l & 3;
            const int jj = l >> 2;
            const float* tsel = (ii == 0) ? t0 : (ii == 1) ? t1 : (ii == 2) ? t2 : t3;
#pragma unroll
            for (int nf = 0; nf < 2; ++nf) {
                const int gn = bn * 64 + wn * 32 + nf * 16 + (lane & 15);
                const float tv = tsel[((size_t)b * 512 + jj) * 512 + gn];
                outp[(((size_t)ii * NB + b) * 512 + jj) * 512 + gn] = acc[mf][nf][j] + tv;
            }
        }
    }
}

// ---------------------------------------------------------------------------
extern "C" void kernel_launch(void* const* d_in, const int* in_sizes, int n_in,
                              void* d_out, int out_size, void* d_ws, size_t ws_size,
                              hipStream_t stream)
{
    const float* t0 = (const float*)d_in[0];
    const float* t1 = (const float*)d_in[1];
    const float* t2 = (const float*)d_in[2];
    const float* t3 = (const float*)d_in[3];
    const float* in_proj_w  = (const float*)d_in[4];
    const float* conv_w     = (const float*)d_in[5];
    const float* conv_b     = (const float*)d_in[6];
    const float* x_proj_w   = (const float*)d_in[7];
    const float* dt_w       = (const float*)d_in[8];
    const float* dt_b       = (const float*)d_in[9];
    const float* A_log      = (const float*)d_in[10];
    const float* D_param    = (const float*)d_in[11];
    const float* out_proj_w = (const float*)d_in[12];
    float* outp = (float*)d_out;

    // workspace carve (~69 MB).  Aliasing timeline (stream-ordered, audited):
    // 1 prep:     W xg_b (@dxp), wib (@xzp), wxb (@hib region)
    // 2 inproj:   R xg_b, wib    -> W xc_raw(f32), zb (@hab region)
    // 3 conv:     R xc_raw, zb   -> W xc_b, xzp (clobbers wib - dead)
    // 4 xproj:    R xc_b, wxb    -> W part (@xc_raw; xc_raw dead)
    // 5 xreduce:  R part         -> W dbc
    // 6 dtproj:   R dbc, xc_b    -> W dxp (clobbers xg_b - dead)
    // 7 scanA:    R dxp, dbc     -> W hab (clobbers zb - dead)
    // 8 combine:  R hab          -> W hib (clobbers wxb - dead)
    // 9 scanC:    R dxp, xzp, dbc, hib -> W yzb (@xc_raw; part dead)
    // 10 outproj: R yzb, Wo, t*  -> W outp
    float* xc_raw = (float*)d_ws;                                    // 16MB
    unsigned short* xc_b = (unsigned short*)(xc_raw + (size_t)MM * DINNER);  // 8MB
    unsigned int* dxp = (unsigned int*)(xc_b + (size_t)MM * DINNER);         // 16MB
    unsigned int* xzp = dxp + (size_t)MM * DINNER;                   // 16MB
    float* dbc  = (float*)(xzp + (size_t)MM * DINNER);               // 1MB
    unsigned int* hab = (unsigned int*)(dbc + (size_t)MM * 64);      // 8MB
    unsigned short* hib = (unsigned short*)(hab + (size_t)NB * DINNER * NSEG * 16); // 4MB
    float* part  = xc_raw;                                           // alias (8MB)
    unsigned short* yzb = (unsigned short*)xc_raw;                   // alias (8MB)
    unsigned short* zb  = (unsigned short*)hab;                      // alias (8MB)
    unsigned short* wxb = hib;                                       // alias (128KB)
    unsigned short* xg_b = (unsigned short*)dxp;                     // alias (4MB)
    unsigned short* wib  = (unsigned short*)xzp;                     // alias (2MB)

    k_prep<<<2112, 256, 0, stream>>>(t0, t1, t2, t3, in_proj_w, x_proj_w, xg_b, wib, wxb);
    k_inproj<<<dim3(32, 16), 256, 0, stream>>>(xg_b, wib, xc_raw, zb);
    k_conv<<<dim3(MM / 16, 4), 256, 0, stream>>>(xc_raw, conv_w, conv_b, zb, xc_b, xzp);
    k_xproj_mfma<<<dim3(32, KCH), 256, 0, stream>>>(xc_b, wxb, part);
    k_xreduce<<<(MM * 64) / 256, 256, 0, stream>>>(part, dbc);
    k_dtproj<<<dim3(MM / 16, 4), 256, 0, stream>>>(dbc, dt_w, dt_b, xc_b, dxp);
    k_scan_partial<<<NSCAN / 256, 256, 0, stream>>>(dxp, dbc, A_log, hab);
    k_scan_combine<<<(NB * DINNER * 64) / 256, 256, 0, stream>>>(hab, hib);
    k_scan_final<<<NSCAN / 256, 256, 0, stream>>>(dxp, xzp, dbc, A_log, D_param, hib, yzb);
    k_outproj<<<dim3(64, 8), 256, 0, stream>>>(yzb, out_proj_w, t0, t1, t2, t3, outp);
}